// Round 4
// baseline (704.043 us; speedup 1.0000x reference)
//
#include <hip/hip_runtime.h>
#include <hip/hip_bf16.h>
#include <stdint.h>

typedef __attribute__((ext_vector_type(8))) short short8;
typedef __attribute__((ext_vector_type(4))) float f32x4;
typedef __attribute__((ext_vector_type(4))) int int4v;

#define LDS_ROW_BYTES 400  // 384 + 16B pad: keeps 16B alignment, spreads bank windows

__device__ __forceinline__ unsigned short f2bf(float f) {
    union { float f; uint32_t u; } v; v.f = f;
    return (unsigned short)((v.u + 0x7FFFu + ((v.u >> 16) & 1u)) >> 16);
}

// Build W[j][k] (bf16, row-major 192x192): W[h*16+oc][g*16+ic] = kernel[cayley[inv[g],h]][oc][ic]
__global__ void build_w_kernel(const float* __restrict__ kern,
                               const int* __restrict__ cayley,
                               const int* __restrict__ inv,
                               unsigned short* __restrict__ Wbf) {
    int i = blockIdx.x * blockDim.x + threadIdx.x;
    if (i >= 192 * 192) return;
    int j = i / 192;
    int k = i - j * 192;
    int h = j >> 4, oc = j & 15;
    int g = k >> 4, ic = k & 15;
    int cidx = cayley[inv[g] * 12 + h];
    Wbf[i] = f2bf(kern[cidx * 256 + oc * 16 + ic]);
}

// out[n][j] = sum_k x[n][k] * W[j][k] + bias[j & 15]
// 1024-thread blocks (16 waves) so ONE 76.8 KB LDS copy of W serves 16 waves
// (R2 showed two 76.8 KB blocks don't co-reside -> 8 waves/CU; this gives 16).
// __launch_bounds__(1024,4): 16 waves = 4/SIMD needs VGPR<=128 (spill-free per R0/R2).
// Each wave: 8 contiguous 16-row strips, register A-prefetch of next strip,
// nontemporal output stores (out never re-read; avoid write-allocate + L3 pollution).
__global__ __launch_bounds__(1024, 4) void gemm_kernel(
    const float* __restrict__ x,
    const unsigned short* __restrict__ Wbf,
    const float* __restrict__ bias,
    float* __restrict__ out, int nstrips, int spw) {
  extern __shared__ unsigned char lds[];  // 192 * 400 = 76800 B
  const int tid  = threadIdx.x;
  const int lane = tid & 63;
  const int wid  = tid >> 6;
  const int l15  = lane & 15;
  const int lhi  = lane >> 4;

  // Stage W (bf16 192x192) into LDS with padded row stride.
  for (int idx = tid; idx < 192 * 24; idx += 1024) {
    int row = idx / 24, o = idx - row * 24;
    int4v v = *(const int4v*)(Wbf + row * 192 + o * 8);
    *(int4v*)(lds + row * LDS_ROW_BYTES + o * 16) = v;
  }
  __syncthreads();

  const float bval = bias[l15];
  // B fragment base for this lane: addr(ct,c) = (ct*16+l15)*400 + c*64 + lhi*16
  const unsigned char* bbase = lds + l15 * LDS_ROW_BYTES + lhi * 16;

  const int gw = blockIdx.x * 16 + wid;   // global wave id
  int strip = gw * spw;
  const int send = min(strip + spw, nstrips);
  if (strip >= send) return;

  f32x4 araw[12];
  {
    const float* xr = x + (size_t)(strip * 16 + l15) * 192 + lhi * 8;
    #pragma unroll
    for (int c = 0; c < 6; ++c) {
      araw[2 * c]     = *(const f32x4*)(xr + c * 32);
      araw[2 * c + 1] = *(const f32x4*)(xr + c * 32 + 4);
    }
  }

  while (strip < send) {
    // Convert current strip's A to bf16 fragments.
    short8 abf[6];
    #pragma unroll
    for (int c = 0; c < 6; ++c) {
      short8 v;
      #pragma unroll
      for (int e = 0; e < 4; ++e) {
        v[e]     = (short)f2bf(araw[2 * c][e]);
        v[e + 4] = (short)f2bf(araw[2 * c + 1][e]);
      }
      abf[c] = v;
    }

    // Issue next strip's A loads (prefetch) before the compute phase.
    const int nxt = strip + 1;
    if (nxt < send) {
      const float* xr = x + (size_t)(nxt * 16 + l15) * 192 + lhi * 8;
      #pragma unroll
      for (int c = 0; c < 6; ++c) {
        araw[2 * c]     = *(const f32x4*)(xr + c * 32);
        araw[2 * c + 1] = *(const f32x4*)(xr + c * 32 + 4);
      }
    }

    float* obase = out + (size_t)(strip * 16 + lhi * 4) * 192 + l15;
    #pragma unroll
    for (int ct = 0; ct < 12; ++ct) {
      const unsigned char* br = bbase + ct * 16 * LDS_ROW_BYTES;
      f32x4 acc = {0.f, 0.f, 0.f, 0.f};
      #pragma unroll
      for (int c = 0; c < 6; ++c) {
        short8 b = *(const short8*)(br + c * 64);
        acc = __builtin_amdgcn_mfma_f32_16x16x32_bf16(abf[c], b, acc, 0, 0, 0);
      }
      // D: col = lane&15 (=l15), row = lhi*4 + r
      #pragma unroll
      for (int r = 0; r < 4; ++r)
        __builtin_nontemporal_store(acc[r] + bval, &obase[(size_t)r * 192 + ct * 16]);
    }
    strip = nxt;
  }
}

extern "C" void kernel_launch(void* const* d_in, const int* in_sizes, int n_in,
                              void* d_out, int out_size, void* d_ws, size_t ws_size,
                              hipStream_t stream) {
    const float* x      = (const float*)d_in[0];
    const float* kern   = (const float*)d_in[1];
    const float* bias   = (const float*)d_in[2];
    const int*   cayley = (const int*)d_in[3];
    const int*   inv    = (const int*)d_in[4];
    float* out = (float*)d_out;
    unsigned short* Wbf = (unsigned short*)d_ws;   // 192*192*2 = 73728 bytes

    const int nrows = in_sizes[0] / 192;
    const int nstrips = nrows / 16;

    build_w_kernel<<<(192 * 192 + 255) / 256, 256, 0, stream>>>(kern, cayley, inv, Wbf);

    const int nblocks = 256;                       // 1 block per CU
    const int nwaves  = nblocks * 16;
    const int spw     = (nstrips + nwaves - 1) / nwaves;   // strips per wave (=8)
    gemm_kernel<<<nblocks, 1024, 192 * LDS_ROW_BYTES, stream>>>(x, Wbf, bias, out, nstrips, spw);
}

// Round 5
// 207.572 us; speedup vs baseline: 3.3918x; 3.3918x over previous
//
#include <hip/hip_runtime.h>
#include <hip/hip_bf16.h>
#include <stdint.h>

typedef __attribute__((ext_vector_type(8))) short short8;
typedef __attribute__((ext_vector_type(4))) float f32x4;

__device__ __forceinline__ unsigned short f2bf(float f) {
    union { float f; uint32_t u; } v; v.f = f;
    return (unsigned short)((v.u + 0x7FFFu + ((v.u >> 16) & 1u)) >> 16);
}

// Build W[j][k] (bf16, row-major 192x192): W[h*16+oc][g*16+ic] = kernel[cayley[inv[g],h]][oc][ic]
__global__ void build_w_kernel(const float* __restrict__ kern,
                               const int* __restrict__ cayley,
                               const int* __restrict__ inv,
                               unsigned short* __restrict__ Wbf) {
    int i = blockIdx.x * blockDim.x + threadIdx.x;
    if (i >= 192 * 192) return;
    int j = i / 192;
    int k = i - j * 192;
    int h = j >> 4, oc = j & 15;
    int g = k >> 4, ic = k & 15;
    int cidx = cayley[inv[g] * 12 + h];
    Wbf[i] = f2bf(kern[cidx * 256 + oc * 16 + ic]);
}

// out[n][j] = sum_k x[n][k] * W[j][k] + bias[j & 15]
// Persistent 256-thread blocks (4 blocks/CU @128 VGPR), no LDS; W streams from L2
// (73.7 KB, fully L2-resident). Each wave owns `spw` contiguous 16-row strips,
// register-prefetching the next strip's x before the compute phase.
// MFMA operands SWAPPED: mfma(w, x) -> D col = x-row (lane&15), row = j.
// Lane (l15,lhi) holds acc[r] = out[strip*16+l15][ct*16+lhi*4+r] -> one
// nontemporal dwordx4 store per (ct,lane). NOTE: bare __launch_bounds__(256)
// only — the 2-arg forms empirically capped VGPR at 64 and spilled (R1/R3).
__global__ __launch_bounds__(256) void gemm_kernel(
    const float* __restrict__ x,
    const unsigned short* __restrict__ Wbf,
    const float* __restrict__ bias,
    float* __restrict__ out, int nstrips, int spw) {
  const int tid  = threadIdx.x;
  const int lane = tid & 63;
  const int wid  = tid >> 6;
  const int l15  = lane & 15;
  const int lhi  = lane >> 4;

  const int gw = blockIdx.x * 4 + wid;    // global wave id
  int strip = gw * spw;
  const int send = min(strip + spw, nstrips);
  if (strip >= send) return;

  // bias for this lane's 4 output features (j = ct*16 + lhi*4 + r -> oc = lhi*4+r)
  const f32x4 bias4 = *(const f32x4*)(bias + lhi * 4);

  f32x4 araw[12];
  {
    const float* xr = x + (size_t)(strip * 16 + l15) * 192 + lhi * 8;
    #pragma unroll
    for (int c = 0; c < 6; ++c) {
      araw[2 * c]     = *(const f32x4*)(xr + c * 32);
      araw[2 * c + 1] = *(const f32x4*)(xr + c * 32 + 4);
    }
  }

  while (strip < send) {
    // Convert current strip's x to bf16 fragments (waits on the 12 loads).
    short8 abf[6];
    #pragma unroll
    for (int c = 0; c < 6; ++c) {
      short8 v;
      #pragma unroll
      for (int e = 0; e < 4; ++e) {
        v[e]     = (short)f2bf(araw[2 * c][e]);
        v[e + 4] = (short)f2bf(araw[2 * c + 1][e]);
      }
      abf[c] = v;
    }

    // Prefetch next strip's x (after conversion frees araw).
    const int nxt = strip + 1;
    if (nxt < send) {
      const float* xr = x + (size_t)(nxt * 16 + l15) * 192 + lhi * 8;
      #pragma unroll
      for (int c = 0; c < 6; ++c) {
        araw[2 * c]     = *(const f32x4*)(xr + c * 32);
        araw[2 * c + 1] = *(const f32x4*)(xr + c * 32 + 4);
      }
    }

    // n-row for this lane's stores: strip*16 + l15
    float* obase = out + (size_t)(strip * 16 + l15) * 192 + lhi * 4;
    #pragma unroll
    for (int ct = 0; ct < 12; ++ct) {
      // W fragment: lane holds W[ct*16 + l15][c*32 + lhi*8 .. +7]
      const unsigned short* wr = Wbf + (size_t)(ct * 16 + l15) * 192 + lhi * 8;
      f32x4 acc = {0.f, 0.f, 0.f, 0.f};
      #pragma unroll
      for (int c = 0; c < 6; ++c) {
        short8 w = *(const short8*)(wr + c * 32);
        acc = __builtin_amdgcn_mfma_f32_16x16x32_bf16(w, abf[c], acc, 0, 0, 0);
      }
      f32x4 res = {acc[0] + bias4[0], acc[1] + bias4[1],
                   acc[2] + bias4[2], acc[3] + bias4[3]};
      __builtin_nontemporal_store(res, (f32x4*)(obase + ct * 16));
    }
    strip = nxt;
  }
}

extern "C" void kernel_launch(void* const* d_in, const int* in_sizes, int n_in,
                              void* d_out, int out_size, void* d_ws, size_t ws_size,
                              hipStream_t stream) {
    const float* x      = (const float*)d_in[0];
    const float* kern   = (const float*)d_in[1];
    const float* bias   = (const float*)d_in[2];
    const int*   cayley = (const int*)d_in[3];
    const int*   inv    = (const int*)d_in[4];
    float* out = (float*)d_out;
    unsigned short* Wbf = (unsigned short*)d_ws;   // 192*192*2 = 73728 bytes

    const int nrows = in_sizes[0] / 192;
    const int nstrips = nrows / 16;                // 32768

    build_w_kernel<<<(192 * 192 + 255) / 256, 256, 0, stream>>>(kern, cayley, inv, Wbf);

    const int nblocks = 1024;                      // 4 per CU, persistent
    const int nwaves  = nblocks * 4;
    const int spw     = (nstrips + nwaves - 1) / nwaves;   // = 8
    gemm_kernel<<<nblocks, 256, 0, stream>>>(x, Wbf, bias, out, nstrips, spw);
}